// Round 14
// baseline (269.749 us; speedup 1.0000x reference)
//
#include <hip/hip_runtime.h>

typedef unsigned int u32;
typedef unsigned short u16;
typedef unsigned char u8;
typedef __bf16 bf16x8 __attribute__((ext_vector_type(8)));
typedef float f32x4 __attribute__((ext_vector_type(4)));
typedef float f32x2 __attribute__((ext_vector_type(2)));

__device__ __forceinline__ u16 f2bf(float f) {
  u32 u = __builtin_bit_cast(u32, f);
  u32 r = (u + 0x7fffu + ((u >> 16) & 1u)) >> 16;   // RTNE
  return (u16)r;
}

// ---------------- fused pre-pass: hist | conv x (bf16 + fp8) | conv W ----------------
__global__ __launch_bounds__(256) void pre_k(const float* __restrict__ x, u16* __restrict__ xbf,
                                             u32* __restrict__ xq,
                                             const float* __restrict__ W, u16* __restrict__ wbf,
                                             const int* __restrict__ dst, int E,
                                             u32* __restrict__ bktTotal, int N, int nbkt,
                                             int nba, int nbx) {
  int b = blockIdx.x, tid = threadIdx.x;
  if (b < nba) {                       // histogram over buckets (dst>>8)
    __shared__ u32 h[512];
    for (int t = tid; t < 512; t += 256) h[t] = 0u;
    __syncthreads();
    int base = b * 8192;
    for (int it = 0; it < 32; it++) {
      int i = base + it * 256 + tid;
      if (i < E) atomicAdd(&h[(u32)dst[i] >> 8], 1u);
    }
    __syncthreads();
    for (int t = tid; t < nbkt; t += 256) {
      u32 c = h[t];
      if (c) atomicAdd(&bktTotal[t], c);
    }
  } else if (b < nba + nbx) {          // x -> xbf (bf16) + xq (fp8 e4m3, natural order)
    int i = (b - nba) * 256 + tid;     // i-th float4
    if (i < N * 32) {
      const float4 v = *(const float4*)(x + (size_t)i * 4);
      ushort4 o = { f2bf(v.x), f2bf(v.y), f2bf(v.z), f2bf(v.w) };
      *(ushort4*)(xbf + (size_t)i * 4) = o;
      u32 p = 0;
      p = __builtin_amdgcn_cvt_pk_fp8_f32(v.x, v.y, p, false);
      p = __builtin_amdgcn_cvt_pk_fp8_f32(v.z, v.w, p, true);
      xq[i] = p;
    }
  } else {                             // W (128 x 256 f32) -> bf16
    int i = (b - nba - nbx) * 256 + tid;
    if (i < 8192) {
      const float4 v = *(const float4*)(W + (size_t)i * 4);
      ushort4 o = { f2bf(v.x), f2bf(v.y), f2bf(v.z), f2bf(v.w) };
      *(ushort4*)(wbf + (size_t)i * 4) = o;
    }
  }
}

// ---------------- bucket scan: starts, cursors, offsets[N] ----------------
__global__ __launch_bounds__(512) void bscan_k(const u32* __restrict__ bktTotal, int nbkt,
                                               int E, int N, u32* __restrict__ start,
                                               u32* __restrict__ cursor, u32* __restrict__ offsets) {
  __shared__ u32 s[512];
  int t = threadIdx.x;
  u32 v = (t < nbkt) ? bktTotal[t] : 0u;
  s[t] = v;
  __syncthreads();
  for (int off = 1; off < 512; off <<= 1) {
    u32 x = (t >= off) ? s[t - off] : 0u;
    __syncthreads();
    s[t] += x;
    __syncthreads();
  }
  u32 excl = s[t] - v;
  if (t < nbkt) { start[t] = excl; cursor[t] = excl; }
  if (t == nbkt - 1) start[nbkt] = excl + v;   // == E
  if (t == 0) offsets[N] = (u32)E;
}

// ---------------- pass A2: partition edges into bucket regions (packed u32) ----------------
__global__ __launch_bounds__(256) void part_k(const int* __restrict__ src, const int* __restrict__ dst,
                                              int E, u32* __restrict__ cursor,
                                              u32* __restrict__ packed, int nbkt) {
  __shared__ u32 h[512];
  for (int t = threadIdx.x; t < 512; t += 256) h[t] = 0u;
  __syncthreads();
  int base = blockIdx.x * 8192;
  for (int it = 0; it < 32; it++) {
    int i = base + it * 256 + threadIdx.x;
    if (i < E) atomicAdd(&h[(u32)dst[i] >> 8], 1u);
  }
  __syncthreads();
  for (int t = threadIdx.x; t < nbkt; t += 256) {
    u32 c = h[t];
    h[t] = c ? atomicAdd(&cursor[t], c) : 0u;
  }
  __syncthreads();
  for (int it = 0; it < 32; it++) {
    int i = base + it * 256 + threadIdx.x;
    if (i < E) {
      u32 d = (u32)dst[i];
      u32 pos = atomicAdd(&h[d >> 8], 1u);      // LDS atomic (u32 fast path)
      packed[pos] = (u32)src[i] | ((d & 255u) << 24);
    }
  }
}

// ---------------- pass B: per-bucket counting sort -> offsets + ssrc ----------------
__global__ __launch_bounds__(256) void bucket_k(const u32* __restrict__ packed,
                                                const u32* __restrict__ start, int N,
                                                u32* __restrict__ offsets, int* __restrict__ ssrc) {
  __shared__ u32 cnt[256];
  __shared__ u32 scn[256];
  __shared__ u32 cur[256];
  int b = blockIdx.x, t = threadIdx.x;
  u32 lo = start[b], hi = start[b + 1];
  cnt[t] = 0u;
  __syncthreads();
  for (u32 j = lo + t; j < hi; j += 256) atomicAdd(&cnt[packed[j] >> 24], 1u);
  __syncthreads();
  u32 v = cnt[t];
  scn[t] = v;
  __syncthreads();
  for (int off = 1; off < 256; off <<= 1) {
    u32 x = (t >= off) ? scn[t - off] : 0u;
    __syncthreads();
    scn[t] += x;
    __syncthreads();
  }
  u32 base = lo + scn[t] - v;
  int node = b * 256 + t;
  if (node < N) offsets[node] = base;
  cur[t] = base;
  __syncthreads();
  for (u32 j = lo + t; j < hi; j += 256) {
    u32 w = packed[j];
    u32 pos = atomicAdd(&cur[w >> 24], 1u);   // LDS atomic (u32)
    ssrc[pos] = (int)(w & 0xFFFFFFu);
  }
}

// ---------------- fused aggregate + GEMM: LDS-staged gather ring ----------------
// Wave-private pipeline (NO barriers): wave streams its 16 nodes' edges as 32-edge
// chunks (4 batches of 8). Per chunk: 1 idx vload -> 4 ds_bpermute -> 4 global_load_lds
// dwordx4 (8 rows/instr, per-lane gather addr) into ping-pong 4KB halves. Chunk c+1 is
// issued BEFORE consuming chunk c; consume waits use EXACT static vmcnt immediates.
// vmcnt derivation (main loop, consume chunk c batch b): younger-than-G_c(b) =
//   G_c(b+1..3) [3-b] + ILOAD(c+2) [1] + G_{c+1}(0..3) [4] = 8-b  -> vmcnt(8-b)
// epilogue (last chunk): younger = G_L(b+1..3) = 3-b -> vmcnt(3-b).

#define DECP(W) { f32x2 q_; \
  q_ = __builtin_amdgcn_cvt_pk_f32_fp8((W).x, false); acc[0] += q_; \
  q_ = __builtin_amdgcn_cvt_pk_f32_fp8((W).x, true);  acc[1] += q_; \
  q_ = __builtin_amdgcn_cvt_pk_f32_fp8((W).y, false); acc[2] += q_; \
  q_ = __builtin_amdgcn_cvt_pk_f32_fp8((W).y, true);  acc[3] += q_; \
  q_ = __builtin_amdgcn_cvt_pk_f32_fp8((W).z, false); acc[4] += q_; \
  q_ = __builtin_amdgcn_cvt_pk_f32_fp8((W).z, true);  acc[5] += q_; \
  q_ = __builtin_amdgcn_cvt_pk_f32_fp8((W).w, false); acc[6] += q_; \
  q_ = __builtin_amdgcn_cvt_pk_f32_fp8((W).w, true);  acc[7] += q_; }

__device__ __forceinline__ void close_node(f32x2* acc, u32 deg, int lrow, int lane,
                                           u16 (*mlds)[136]) {
#pragma unroll
  for (int m = 1; m <= 4; m <<= 1) {
#pragma unroll
    for (int i = 0; i < 8; i++) {
      acc[i].x += __shfl_xor(acc[i].x, m);
      acc[i].y += __shfl_xor(acc[i].y, m);
    }
  }
  float inv = 1.0f / (float)(deg ? deg : 1u);
  if ((lane & 7) == 0) {
    int s8 = lane >> 3;
    u32 o[8];
#pragma unroll
    for (int k = 0; k < 8; k++)
      o[k] = (u32)f2bf(acc[k].x * inv) | ((u32)f2bf(acc[k].y * inv) << 16);
    u32* mp = (u32*)&mlds[lrow][s8 * 16];
    *(uint4*)(mp + 0) = uint4{o[0], o[1], o[2], o[3]};
    *(uint4*)(mp + 4) = uint4{o[4], o[5], o[6], o[7]};
  }
#pragma unroll
  for (int i = 0; i < 8; i++) acc[i] = f32x2{0.f, 0.f};
}

__device__ __forceinline__ void consume_batch(uint4 w, u32 p, int lane, f32x2* acc,
                                              u32& s0node, u32& s1c, int& cnode, int nlast,
                                              int nbaseblk, const u32* __restrict__ offsets,
                                              u16 (*mlds)[136]) {
  u32 pos = p + (u32)(lane & 7);
  u32 pend = p + 8u;
  for (;;) {
    if (cnode > nlast) break;
    if (s1c >= pend) {                          // rest of batch inside current node
      if (s0node <= p) { DECP(w) }
      else {
        bool in = pos >= s0node;
        uint4 wm = { in ? w.x : 0u, in ? w.y : 0u, in ? w.z : 0u, in ? w.w : 0u };
        DECP(wm)
      }
      break;
    }
    {                                            // node ends mid-batch at s1c
      bool in = (pos >= s0node) && (pos < s1c);
      uint4 wm = { in ? w.x : 0u, in ? w.y : 0u, in ? w.z : 0u, in ? w.w : 0u };
      DECP(wm)
    }
    close_node(acc, s1c - s0node, cnode - nbaseblk, lane, mlds);
    cnode++;
    s0node = s1c;
    if (cnode <= nlast) s1c = offsets[cnode + 1];
  }
}

#define ILOAD(CB) { u32 jj = (CB) + (u32)(lane & 31); if (jj > Em1) jj = Em1; \
                    vidx = (u32)ssrc[jj]; }

#define BPERM() { int pb = (lane & 7) * 4; \
    bp0 = __builtin_amdgcn_ds_bpermute(pb,      (int)vidx); \
    bp1 = __builtin_amdgcn_ds_bpermute(pb + 32, (int)vidx); \
    bp2 = __builtin_amdgcn_ds_bpermute(pb + 64, (int)vidx); \
    bp3 = __builtin_amdgcn_ds_bpermute(pb + 96, (int)vidx); }

#define GISS(PAR, B, BP) { \
    const char* gsrc = xqb + (((size_t)(u32)(BP)) << 7) + ((lane >> 3) << 4); \
    __builtin_amdgcn_global_load_lds((const u32*)gsrc, \
        (u32*)(stg + ((PAR) * 4 + (B)) * 1024), 16, 0, 0); }

#define CONS(PAR, B, IMM, CB) { \
    asm volatile("s_waitcnt vmcnt(" #IMM ")" ::: "memory"); \
    uint4 w = *(const uint4*)(stg + ((PAR) * 4 + (B)) * 1024 + (lane << 4)); \
    consume_batch(w, (CB) + (B) * 8u, lane, acc, s0node, s1c, cnode, nlast, \
                  nbaseblk, offsets, mlds); }

__global__ __launch_bounds__(256) void fuse_k(const int* __restrict__ ssrc,
                                              const u32* __restrict__ offsets,
                                              const u32* __restrict__ xq,
                                              const u16* __restrict__ xbf,
                                              const u16* __restrict__ wbf,
                                              const float* __restrict__ bias,
                                              float* __restrict__ out, int N, int E) {
  __shared__ u8 stg_all[4][8192];               // per-wave ping-pong stage (2 x 4KB)
  __shared__ u16 mlds[64][136];                 // means, padded stride
  int wv = threadIdx.x >> 6, lane = threadIdx.x & 63;
  int nbaseblk = blockIdx.x * 64;
  int wbase = nbaseblk + wv * 16;
  const char* xqb = (const char*)xq;
  u8* stg = stg_all[wv];

  if (wbase < N) {
    int nlast = wbase + 15; if (nlast > N - 1) nlast = N - 1;
    u32 S0 = offsets[wbase];
    u32 S1 = offsets[nlast + 1];
    u32 Em1 = (u32)E - 1u;
    int nc = (int)((S1 - S0 + 31u) >> 5);

    int cnode = wbase;
    u32 s0node = S0;
    u32 s1c = offsets[wbase + 1];
    f32x2 acc[8];
#pragma unroll
    for (int i = 0; i < 8; i++) acc[i] = f32x2{0.f, 0.f};

    if (nc > 0) {
      u32 vidx; int bp0, bp1, bp2, bp3;
      ILOAD(S0)                                  // idx chunk 0
      BPERM()                                    // slots chunk 0
      ILOAD(S0 + 32u)                            // idx chunk 1 (clamped if absent)
      GISS(0, 0, bp0) GISS(0, 1, bp1) GISS(0, 2, bp2) GISS(0, 3, bp3)
      for (int c = 0; c < nc - 1; c++) {
        int par = c & 1, npar = par ^ 1;
        BPERM()                                  // slots chunk c+1
        ILOAD(S0 + ((u32)c + 2u) * 32u)          // idx chunk c+2 (clamped; exact count pad)
        GISS(npar, 0, bp0) GISS(npar, 1, bp1) GISS(npar, 2, bp2) GISS(npar, 3, bp3)
        u32 cb = S0 + (u32)c * 32u;
        CONS(par, 0, 8, cb) CONS(par, 1, 7, cb) CONS(par, 2, 6, cb) CONS(par, 3, 5, cb)
      }
      {
        int par = (nc - 1) & 1;
        u32 cb = S0 + ((u32)nc - 1u) * 32u;
        CONS(par, 0, 3, cb) CONS(par, 1, 2, cb) CONS(par, 2, 1, cb) CONS(par, 3, 0, cb)
      }
    }
    while (cnode <= nlast) {                     // remaining (incl. deg-0 tail) nodes
      close_node(acc, s1c - s0node, cnode - nbaseblk, lane, mlds);
      cnode++;
      s0node = s1c;
      if (cnode <= nlast) s1c = offsets[cnode + 1];
    }

    // ---- phase 2: 16-row GEMM strip (own wave's mlds rows; no barrier needed) ----
    int la = lane & 15, lb = lane >> 4;
    bf16x8 a[8];
    const u16* ab = xbf + ((size_t)(wbase + la) << 7) + lb * 8;
#pragma unroll
    for (int kb = 0; kb < 4; kb++) a[kb] = *(const bf16x8*)(ab + kb * 32);
#pragma unroll
    for (int kb = 0; kb < 4; kb++)
      a[4 + kb] = *(const bf16x8*)(&mlds[wv * 16 + la][kb * 32 + lb * 8]);

#pragma unroll
    for (int ct = 0; ct < 8; ct++) {
      f32x4 accr = { 0.f, 0.f, 0.f, 0.f };
      const u16* bbase = wbf + ((size_t)(ct * 16 + la) << 8) + lb * 8;
#pragma unroll
      for (int kb = 0; kb < 8; kb++) {
        bf16x8 bv = *(const bf16x8*)(bbase + kb * 32);
        accr = __builtin_amdgcn_mfma_f32_16x16x32_bf16(a[kb], bv, accr, 0, 0, 0);
      }
      float bc = bias[ct * 16 + la];
#pragma unroll
      for (int jj = 0; jj < 4; jj++) {
        int rr = wbase + lb * 4 + jj;
        if (rr < N) out[((size_t)rr << 7) + ct * 16 + la] = accr[jj] + bc;
      }
    }
  }
}

extern "C" void kernel_launch(void* const* d_in, const int* in_sizes, int n_in,
                              void* d_out, int out_size, void* d_ws, size_t ws_size,
                              hipStream_t stream) {
  const float* x    = (const float*)d_in[0];
  const int*   ei   = (const int*)d_in[1];
  const float* W    = (const float*)d_in[2];
  const float* bias = (const float*)d_in[3];
  const int N = in_sizes[0] / 128;
  const int E = in_sizes[1] / 2;
  const int nbkt = (N + 255) >> 8;           // 256-node buckets
  const int* src = ei;
  const int* dst = ei + E;
  float* out = (float*)d_out;

  // transient CSR-build scratch in d_out (dead before fuse_k writes out):
  u32* packed   = (u32*)d_out;               // E
  u32* bktTotal = packed + E;                // nbkt
  u32* start    = bktTotal + nbkt;           // nbkt+1
  u32* cursor   = start + nbkt + 1;          // nbkt

  char* ws = (char*)d_ws;
  u32* offsets = (u32*)ws;                   // N+1
  size_t off = ((size_t)(N + 1) * 4 + 255) & ~(size_t)255;
  int* ssrc = (int*)(ws + off);              // E
  off += (size_t)E * 4;
  off = (off + 255) & ~(size_t)255;
  u16* xbf = (u16*)(ws + off);               // N*128 bf16
  off += (size_t)N * 128 * 2;
  off = (off + 255) & ~(size_t)255;
  u32* xq = (u32*)(ws + off);                // N*32 u32 (natural-order fp8)
  off += (size_t)N * 128;
  off = (off + 255) & ~(size_t)255;
  u16* wbf = (u16*)(ws + off);               // 128*256 bf16

  const int nbx = (N * 32 + 255) / 256;
  const int nba = (E + 8191) / 8192;
  hipMemsetAsync(bktTotal, 0, (size_t)nbkt * 4, stream);
  pre_k<<<nba + nbx + 32, 256, 0, stream>>>(x, xbf, xq, W, wbf, dst, E, bktTotal, N, nbkt, nba, nbx);
  bscan_k<<<1, 512, 0, stream>>>(bktTotal, nbkt, E, N, start, cursor, offsets);
  part_k<<<nba, 256, 0, stream>>>(src, dst, E, cursor, packed, nbkt);
  bucket_k<<<nbkt, 256, 0, stream>>>(packed, start, N, offsets, ssrc);
  fuse_k<<<(N + 63) / 64, 256, 0, stream>>>(ssrc, offsets, xq, xbf, wbf, bias, out, N, E);
}

// Round 15
// 244.348 us; speedup vs baseline: 1.1040x; 1.1040x over previous
//
#include <hip/hip_runtime.h>

typedef unsigned int u32;
typedef unsigned short u16;
typedef unsigned char u8;
typedef _Float16 half8 __attribute__((ext_vector_type(8)));
typedef _Float16 h2 __attribute__((ext_vector_type(2)));
typedef float f32x4 __attribute__((ext_vector_type(4)));

__device__ __forceinline__ u16 f2bf(float f) {
  u32 u = __builtin_bit_cast(u32, f);
  u32 r = (u + 0x7fffu + ((u >> 16) & 1u)) >> 16;   // RTNE
  return (u16)r;
}

// ---------------- fused pre-pass: hist | conv x->f16 | conv W->f16 ----------------
// bktTotal must be zeroed (hipMemsetAsync) before this kernel.
__global__ __launch_bounds__(256) void pre_k(const float* __restrict__ x, u16* __restrict__ xh,
                                             const float* __restrict__ W, u16* __restrict__ wh,
                                             const int* __restrict__ dst, int E,
                                             u32* __restrict__ bktTotal, int N, int nbkt,
                                             int nba, int nbx) {
  int b = blockIdx.x, tid = threadIdx.x;
  if (b < nba) {                       // histogram over buckets (dst>>8)
    __shared__ u32 h[512];
    for (int t = tid; t < 512; t += 256) h[t] = 0u;
    __syncthreads();
    int base = b * 8192;
    for (int it = 0; it < 32; it++) {
      int i = base + it * 256 + tid;
      if (i < E) atomicAdd(&h[(u32)dst[i] >> 8], 1u);
    }
    __syncthreads();
    for (int t = tid; t < nbkt; t += 256) {
      u32 c = h[t];
      if (c) atomicAdd(&bktTotal[t], c);
    }
  } else if (b < nba + nbx) {          // x (N x 128 f32) -> f16
    int i = (b - nba) * 256 + tid;     // i-th float4
    if (i < N * 32) {
      const float4 v = *(const float4*)(x + (size_t)i * 4);
      u32 p0 = __builtin_bit_cast(u32, __builtin_amdgcn_cvt_pkrtz(v.x, v.y));
      u32 p1 = __builtin_bit_cast(u32, __builtin_amdgcn_cvt_pkrtz(v.z, v.w));
      *(uint2*)(xh + (size_t)i * 4) = uint2{p0, p1};
    }
  } else {                             // W (128 x 256 f32) -> f16
    int i = (b - nba - nbx) * 256 + tid;
    if (i < 8192) {
      const float4 v = *(const float4*)(W + (size_t)i * 4);
      u32 p0 = __builtin_bit_cast(u32, __builtin_amdgcn_cvt_pkrtz(v.x, v.y));
      u32 p1 = __builtin_bit_cast(u32, __builtin_amdgcn_cvt_pkrtz(v.z, v.w));
      *(uint2*)(wh + (size_t)i * 4) = uint2{p0, p1};
    }
  }
}

// ---------------- bucket scan: starts, cursors, offsets[N] ----------------
__global__ __launch_bounds__(512) void bscan_k(const u32* __restrict__ bktTotal, int nbkt,
                                               int E, int N, u32* __restrict__ start,
                                               u32* __restrict__ cursor, u32* __restrict__ offsets) {
  __shared__ u32 s[512];
  int t = threadIdx.x;
  u32 v = (t < nbkt) ? bktTotal[t] : 0u;
  s[t] = v;
  __syncthreads();
  for (int off = 1; off < 512; off <<= 1) {
    u32 x = (t >= off) ? s[t - off] : 0u;
    __syncthreads();
    s[t] += x;
    __syncthreads();
  }
  u32 excl = s[t] - v;
  if (t < nbkt) { start[t] = excl; cursor[t] = excl; }
  if (t == nbkt - 1) start[nbkt] = excl + v;   // == E
  if (t == 0) offsets[N] = (u32)E;
}

// ---------------- pass A2: partition edges into bucket regions (packed u32) ----------------
__global__ __launch_bounds__(256) void part_k(const int* __restrict__ src, const int* __restrict__ dst,
                                              int E, u32* __restrict__ cursor,
                                              u32* __restrict__ packed, int nbkt) {
  __shared__ u32 h[512];
  for (int t = threadIdx.x; t < 512; t += 256) h[t] = 0u;
  __syncthreads();
  int base = blockIdx.x * 8192;
  for (int it = 0; it < 32; it++) {
    int i = base + it * 256 + threadIdx.x;
    if (i < E) atomicAdd(&h[(u32)dst[i] >> 8], 1u);
  }
  __syncthreads();
  for (int t = threadIdx.x; t < nbkt; t += 256) {
    u32 c = h[t];
    h[t] = c ? atomicAdd(&cursor[t], c) : 0u;   // reserve contiguous per-(block,bucket) range
  }
  __syncthreads();
  for (int it = 0; it < 32; it++) {
    int i = base + it * 256 + threadIdx.x;
    if (i < E) {
      u32 d = (u32)dst[i];
      u32 pos = atomicAdd(&h[d >> 8], 1u);      // LDS atomic (u32 fast path)
      packed[pos] = (u32)src[i] | ((d & 255u) << 24);
    }
  }
}

// ---------------- pass B: counting sort -> offsets + ssrc + 32-node degree-rank perm ----------------
__global__ __launch_bounds__(256) void bucket_k(const u32* __restrict__ packed,
                                                const u32* __restrict__ start, int N,
                                                u32* __restrict__ offsets, int* __restrict__ ssrc,
                                                u8* __restrict__ nodeperm) {
  __shared__ u32 cnt[256];
  __shared__ u32 scn[256];
  __shared__ u32 cur[256];
  int b = blockIdx.x, t = threadIdx.x;
  u32 lo = start[b], hi = start[b + 1];
  cnt[t] = 0u;
  __syncthreads();
  for (u32 j = lo + t; j < hi; j += 256) atomicAdd(&cnt[packed[j] >> 24], 1u);
  __syncthreads();
  u32 v = cnt[t];
  scn[t] = v;
  __syncthreads();
  for (int off = 1; off < 256; off <<= 1) {
    u32 x = (t >= off) ? scn[t - off] : 0u;
    __syncthreads();
    scn[t] += x;
    __syncthreads();
  }
  u32 base = lo + scn[t] - v;     // exclusive position of this node's segment
  int node = b * 256 + t;
  if (node < N) offsets[node] = base;
  cur[t] = base;
  __syncthreads();
  for (u32 j = lo + t; j < hi; j += 256) {
    u32 w = packed[j];
    u32 pos = atomicAdd(&cur[w >> 24], 1u);   // LDS atomic (u32)
    ssrc[pos] = (int)(w & 0xFFFFFFu);
  }
  // degree-rank permutation per 32-node group (ascending degree, stable)
  {
    int g = t >> 5, l = t & 31;
    u32 mykey = cnt[t] * 256u + (u32)l;
    const u32* cg = &cnt[g * 32];
    u32 rank = 0;
#pragma unroll 8
    for (int l2 = 0; l2 < 32; l2++) {
      u32 k2 = cg[l2] * 256u + (u32)l2;
      rank += (k2 < mykey) ? 1u : 0u;
    }
    nodeperm[(size_t)b * 256 + g * 32 + rank] = (u8)l;
  }
}

// ---------------- fused aggregate + GEMM, 4 waves / 32 nodes per block ----------------
// Phase 1: 16-lane sub-group owns one node (lane = 8 f16 feats, dwordx4); 4 degree-matched
// nodes concurrent per wave, 2 rounds (8 nodes/wave); packed f16 accumulation (4 instr/edge);
// next-quad idx prefetch. Grid = N/32 blocks -> ~48 waves/CU oversubscribed.
// Phase 2: 2 strips x 2 ct-halves; f16 MFMA: A = [xh rows | LDS means], B = wh.
#define ACC4(V) { a0 += __builtin_bit_cast(h2, (V).x); a1 += __builtin_bit_cast(h2, (V).y); \
                  a2 += __builtin_bit_cast(h2, (V).z); a3 += __builtin_bit_cast(h2, (V).w); }

__global__ __launch_bounds__(256) void fuse_k(const int* __restrict__ ssrc,
                                              const u32* __restrict__ offsets,
                                              const u16* __restrict__ xh,
                                              const u16* __restrict__ wh,
                                              const float* __restrict__ bias,
                                              const u8* __restrict__ nodeperm,
                                              float* __restrict__ out, int N) {
  __shared__ u16 mlds[32][136];               // means (f16), padded stride
  int wv = threadIdx.x >> 6, lane = threadIdx.x & 63;
  int sub = lane >> 4, cl = lane & 15;
  int nbase = blockIdx.x * 32;
  const char* xhb = (const char*)xh;
  const int lofs = cl << 4;                   // 16B slice of the 256B row

  // ---- phase 1: 2 rounds x 4 concurrent degree-matched nodes per wave ----
  for (int r = 0; r < 2; r++) {
    int ln = nodeperm[(size_t)nbase + r * 16 + wv * 4 + sub];
    int node = nbase + ln;
    h2 a0{0,0}, a1{0,0}, a2{0,0}, a3{0,0};
    u32 deg = 0;
    if (node < N) {
      u32 s0 = offsets[node], s1 = offsets[node + 1];
      deg = s1 - s0;
      u32 j = s0;
      u32 nq = deg >> 2;
      if (nq) {
        uint4 iA = *(const uint4*)(ssrc + j);
        for (u32 q = 1; q < nq; q++) {
          uint4 iN = *(const uint4*)(ssrc + j + 4);   // prefetch next quad's indices
          uint4 v0 = *(const uint4*)(xhb + ((size_t)iA.x << 8) + lofs);
          uint4 v1 = *(const uint4*)(xhb + ((size_t)iA.y << 8) + lofs);
          uint4 v2 = *(const uint4*)(xhb + ((size_t)iA.z << 8) + lofs);
          uint4 v3 = *(const uint4*)(xhb + ((size_t)iA.w << 8) + lofs);
          ACC4(v0) ACC4(v1) ACC4(v2) ACC4(v3)
          iA = iN; j += 4;
        }
        {
          uint4 v0 = *(const uint4*)(xhb + ((size_t)iA.x << 8) + lofs);
          uint4 v1 = *(const uint4*)(xhb + ((size_t)iA.y << 8) + lofs);
          uint4 v2 = *(const uint4*)(xhb + ((size_t)iA.z << 8) + lofs);
          uint4 v3 = *(const uint4*)(xhb + ((size_t)iA.w << 8) + lofs);
          ACC4(v0) ACC4(v1) ACC4(v2) ACC4(v3)
          j += 4;
        }
      }
      for (; j < s1; j++) {
        int e = ssrc[j];
        uint4 v = *(const uint4*)(xhb + ((size_t)e << 8) + lofs);
        ACC4(v)
      }
    }
    _Float16 ih = (_Float16)(1.0f / (float)(deg ? deg : 1u));
    h2 iv{ih, ih};
    h2 m0 = a0 * iv, m1 = a1 * iv, m2 = a2 * iv, m3 = a3 * iv;
    uint4 o{__builtin_bit_cast(u32, m0), __builtin_bit_cast(u32, m1),
            __builtin_bit_cast(u32, m2), __builtin_bit_cast(u32, m3)};
    *(uint4*)&mlds[ln][cl * 8] = o;           // 16 lanes cover all 128 feats
  }
  __syncthreads();

  // ---- phase 2: 2 strips x 2 col-halves; wave = (strip, half); f16 MFMA ----
  int la = lane & 15, lb = lane >> 4;
  int strip = wv & 1, ch = wv >> 1;
  int rbase = nbase + strip * 16;
  half8 a[8];
  const u16* ab = xh + ((size_t)(rbase + la) << 7) + lb * 8;
#pragma unroll
  for (int kb = 0; kb < 4; kb++) a[kb] = *(const half8*)(ab + kb * 32);
#pragma unroll
  for (int kb = 0; kb < 4; kb++)
    a[4 + kb] = *(const half8*)(&mlds[strip * 16 + la][kb * 32 + lb * 8]);

#pragma unroll
  for (int c = 0; c < 4; c++) {
    int ct = ch * 4 + c;
    f32x4 acc = { 0.f, 0.f, 0.f, 0.f };
    const u16* bbase = wh + ((size_t)(ct * 16 + la) << 8) + lb * 8;
#pragma unroll
    for (int kb = 0; kb < 8; kb++) {
      half8 b = *(const half8*)(bbase + kb * 32);
      acc = __builtin_amdgcn_mfma_f32_16x16x32_f16(a[kb], b, acc, 0, 0, 0);
    }
    float bc = bias[ct * 16 + la];
#pragma unroll
    for (int jj = 0; jj < 4; jj++) {
      int rr = rbase + lb * 4 + jj;
      if (rr < N) out[((size_t)rr << 7) + ct * 16 + la] = acc[jj] + bc;
    }
  }
}

extern "C" void kernel_launch(void* const* d_in, const int* in_sizes, int n_in,
                              void* d_out, int out_size, void* d_ws, size_t ws_size,
                              hipStream_t stream) {
  const float* x    = (const float*)d_in[0];
  const int*   ei   = (const int*)d_in[1];
  const float* W    = (const float*)d_in[2];
  const float* bias = (const float*)d_in[3];
  const int N = in_sizes[0] / 128;
  const int E = in_sizes[1] / 2;
  const int nbkt = (N + 255) >> 8;           // 256-node buckets
  const int* src = ei;
  const int* dst = ei + E;
  float* out = (float*)d_out;

  // transient CSR-build scratch in d_out (dead before fuse_k writes out):
  u32* packed   = (u32*)d_out;               // E
  u32* bktTotal = packed + E;                // nbkt
  u32* start    = bktTotal + nbkt;           // nbkt+1
  u32* cursor   = start + nbkt + 1;          // nbkt

  char* ws = (char*)d_ws;
  u32* offsets = (u32*)ws;                   // N+1
  size_t off = ((size_t)(N + 1) * 4 + 255) & ~(size_t)255;
  int* ssrc = (int*)(ws + off);              // E
  off += (size_t)E * 4;
  off = (off + 255) & ~(size_t)255;
  u16* xh = (u16*)(ws + off);                // N*128 f16
  off += (size_t)N * 128 * 2;
  off = (off + 255) & ~(size_t)255;
  u16* wh = (u16*)(ws + off);                // 128*256 f16
  off += (size_t)128 * 256 * 2;
  off = (off + 255) & ~(size_t)255;
  u8* nodeperm = (u8*)(ws + off);            // nbkt*256 bytes

  const int nbx = (N * 32 + 255) / 256;
  const int nba = (E + 8191) / 8192;
  hipMemsetAsync(bktTotal, 0, (size_t)nbkt * 4, stream);
  pre_k<<<nba + nbx + 32, 256, 0, stream>>>(x, xh, W, wh, dst, E, bktTotal, N, nbkt, nba, nbx);
  bscan_k<<<1, 512, 0, stream>>>(bktTotal, nbkt, E, N, start, cursor, offsets);
  part_k<<<nba, 256, 0, stream>>>(src, dst, E, cursor, packed, nbkt);
  bucket_k<<<nbkt, 256, 0, stream>>>(packed, start, N, offsets, ssrc, nodeperm);
  fuse_k<<<(N + 31) / 32, 256, 0, stream>>>(ssrc, offsets, xh, wh, bias, nodeperm, out, N);
}

// Round 16
// 208.058 us; speedup vs baseline: 1.2965x; 1.1744x over previous
//
#include <hip/hip_runtime.h>

typedef unsigned int u32;
typedef unsigned short u16;
typedef unsigned char u8;
typedef _Float16 half8 __attribute__((ext_vector_type(8)));
typedef float f32x4 __attribute__((ext_vector_type(4)));
typedef float f32x2 __attribute__((ext_vector_type(2)));

// ---------------- fused pre-pass: hist | conv x->f16+fp8 | conv W->f16 ----------------
// bktTotal must be zeroed (hipMemsetAsync) before this kernel.
__global__ __launch_bounds__(256) void pre_k(const float* __restrict__ x, u16* __restrict__ xh,
                                             u32* __restrict__ xq,
                                             const float* __restrict__ W, u16* __restrict__ wh,
                                             const int* __restrict__ dst, int E,
                                             u32* __restrict__ bktTotal, int N, int nbkt,
                                             int nba, int nbx) {
  int b = blockIdx.x, tid = threadIdx.x;
  if (b < nba) {                       // histogram over buckets (dst>>8)
    __shared__ u32 h[512];
    for (int t = tid; t < 512; t += 256) h[t] = 0u;
    __syncthreads();
    int base = b * 8192;
    for (int it = 0; it < 32; it++) {
      int i = base + it * 256 + tid;
      if (i < E) atomicAdd(&h[(u32)dst[i] >> 8], 1u);
    }
    __syncthreads();
    for (int t = tid; t < nbkt; t += 256) {
      u32 c = h[t];
      if (c) atomicAdd(&bktTotal[t], c);
    }
  } else if (b < nba + nbx) {          // x (N x 128 f32) -> f16 (GEMM) + fp8 (gather)
    int i = (b - nba) * 256 + tid;     // i-th float4
    if (i < N * 32) {
      const float4 v = *(const float4*)(x + (size_t)i * 4);
      u32 p0 = __builtin_bit_cast(u32, __builtin_amdgcn_cvt_pkrtz(v.x, v.y));
      u32 p1 = __builtin_bit_cast(u32, __builtin_amdgcn_cvt_pkrtz(v.z, v.w));
      *(uint2*)(xh + (size_t)i * 4) = uint2{p0, p1};
      u32 q = 0;
      q = __builtin_amdgcn_cvt_pk_fp8_f32(v.x, v.y, q, false);
      q = __builtin_amdgcn_cvt_pk_fp8_f32(v.z, v.w, q, true);
      xq[i] = q;
    }
  } else {                             // W (128 x 256 f32) -> f16
    int i = (b - nba - nbx) * 256 + tid;
    if (i < 8192) {
      const float4 v = *(const float4*)(W + (size_t)i * 4);
      u32 p0 = __builtin_bit_cast(u32, __builtin_amdgcn_cvt_pkrtz(v.x, v.y));
      u32 p1 = __builtin_bit_cast(u32, __builtin_amdgcn_cvt_pkrtz(v.z, v.w));
      *(uint2*)(wh + (size_t)i * 4) = uint2{p0, p1};
    }
  }
}

// ---------------- bucket scan: starts, cursors, offsets[N] ----------------
__global__ __launch_bounds__(512) void bscan_k(const u32* __restrict__ bktTotal, int nbkt,
                                               int E, int N, u32* __restrict__ start,
                                               u32* __restrict__ cursor, u32* __restrict__ offsets) {
  __shared__ u32 s[512];
  int t = threadIdx.x;
  u32 v = (t < nbkt) ? bktTotal[t] : 0u;
  s[t] = v;
  __syncthreads();
  for (int off = 1; off < 512; off <<= 1) {
    u32 x = (t >= off) ? s[t - off] : 0u;
    __syncthreads();
    s[t] += x;
    __syncthreads();
  }
  u32 excl = s[t] - v;
  if (t < nbkt) { start[t] = excl; cursor[t] = excl; }
  if (t == nbkt - 1) start[nbkt] = excl + v;   // == E
  if (t == 0) offsets[N] = (u32)E;
}

// ---------------- pass A2: partition edges into bucket regions (packed u32) ----------------
__global__ __launch_bounds__(256) void part_k(const int* __restrict__ src, const int* __restrict__ dst,
                                              int E, u32* __restrict__ cursor,
                                              u32* __restrict__ packed, int nbkt) {
  __shared__ u32 h[512];
  for (int t = threadIdx.x; t < 512; t += 256) h[t] = 0u;
  __syncthreads();
  int base = blockIdx.x * 8192;
  for (int it = 0; it < 32; it++) {
    int i = base + it * 256 + threadIdx.x;
    if (i < E) atomicAdd(&h[(u32)dst[i] >> 8], 1u);
  }
  __syncthreads();
  for (int t = threadIdx.x; t < nbkt; t += 256) {
    u32 c = h[t];
    h[t] = c ? atomicAdd(&cursor[t], c) : 0u;   // reserve contiguous per-(block,bucket) range
  }
  __syncthreads();
  for (int it = 0; it < 32; it++) {
    int i = base + it * 256 + threadIdx.x;
    if (i < E) {
      u32 d = (u32)dst[i];
      u32 pos = atomicAdd(&h[d >> 8], 1u);      // LDS atomic (u32 fast path)
      packed[pos] = (u32)src[i] | ((d & 255u) << 24);
    }
  }
}

// ---------------- pass B: counting sort -> offsets + ssrc + 32-node degree-rank perm ----------------
__global__ __launch_bounds__(256) void bucket_k(const u32* __restrict__ packed,
                                                const u32* __restrict__ start, int N,
                                                u32* __restrict__ offsets, int* __restrict__ ssrc,
                                                u8* __restrict__ nodeperm) {
  __shared__ u32 cnt[256];
  __shared__ u32 scn[256];
  __shared__ u32 cur[256];
  int b = blockIdx.x, t = threadIdx.x;
  u32 lo = start[b], hi = start[b + 1];
  cnt[t] = 0u;
  __syncthreads();
  for (u32 j = lo + t; j < hi; j += 256) atomicAdd(&cnt[packed[j] >> 24], 1u);
  __syncthreads();
  u32 v = cnt[t];
  scn[t] = v;
  __syncthreads();
  for (int off = 1; off < 256; off <<= 1) {
    u32 x = (t >= off) ? scn[t - off] : 0u;
    __syncthreads();
    scn[t] += x;
    __syncthreads();
  }
  u32 base = lo + scn[t] - v;     // exclusive position of this node's segment
  int node = b * 256 + t;
  if (node < N) offsets[node] = base;
  cur[t] = base;
  __syncthreads();
  for (u32 j = lo + t; j < hi; j += 256) {
    u32 w = packed[j];
    u32 pos = atomicAdd(&cur[w >> 24], 1u);   // LDS atomic (u32)
    ssrc[pos] = (int)(w & 0xFFFFFFu);
  }
  // degree-rank permutation per 32-node group (ascending degree, stable)
  {
    int g = t >> 5, l = t & 31;
    u32 mykey = cnt[t] * 256u + (u32)l;
    const u32* cg = &cnt[g * 32];
    u32 rank = 0;
#pragma unroll 8
    for (int l2 = 0; l2 < 32; l2++) {
      u32 k2 = cg[l2] * 256u + (u32)l2;
      rank += (k2 < mykey) ? 1u : 0u;
    }
    nodeperm[(size_t)b * 256 + g * 32 + rank] = (u8)l;
  }
}

// ---------------- fused aggregate + GEMM, 4 waves / 32 nodes per block ----------------
// Phase 1 (R12-proven): 16-lane sub-group owns one fp8-row node (lane = 8 fp8 feats,
// dwordx2); 4 degree-matched nodes concurrent per wave, 2 rounds; next-quad idx prefetch.
// Grid = N/32 blocks (3125) fills residency (occupancy lever vs R12's 64-node blocks).
// Phase 2 (R15-proven): 2 strips x 2 ct-halves; f16 MFMA: A = [xh rows | LDS means], B = wh.
#define DECV(vv, A0, A1, A2, A3) { f32x2 p;                              \
    p = __builtin_amdgcn_cvt_pk_f32_fp8((vv).x, false); A0 += p;         \
    p = __builtin_amdgcn_cvt_pk_f32_fp8((vv).x, true);  A1 += p;         \
    p = __builtin_amdgcn_cvt_pk_f32_fp8((vv).y, false); A2 += p;         \
    p = __builtin_amdgcn_cvt_pk_f32_fp8((vv).y, true);  A3 += p; }

__global__ __launch_bounds__(256) void fuse_k(const int* __restrict__ ssrc,
                                              const u32* __restrict__ offsets,
                                              const u32* __restrict__ xq,
                                              const u16* __restrict__ xh,
                                              const u16* __restrict__ wh,
                                              const float* __restrict__ bias,
                                              const u8* __restrict__ nodeperm,
                                              float* __restrict__ out, int N) {
  __shared__ u16 mlds[32][136];               // means (f16), padded stride
  int wv = threadIdx.x >> 6, lane = threadIdx.x & 63;
  int sub = lane >> 4, cl = lane & 15;
  int nbase = blockIdx.x * 32;

  // ---- phase 1: 2 rounds x 4 concurrent degree-matched nodes per wave ----
  for (int r = 0; r < 2; r++) {
    int ln = nodeperm[(size_t)nbase + r * 16 + wv * 4 + sub];
    int node = nbase + ln;
    f32x2 A0{0.f,0.f}, A1{0.f,0.f}, A2{0.f,0.f}, A3{0.f,0.f};
    u32 deg = 0;
    if (node < N) {
      u32 s0 = offsets[node], s1 = offsets[node + 1];
      deg = s1 - s0;
      u32 j = s0;
      u32 nq = deg >> 2;
      if (nq) {
        uint4 iA = *(const uint4*)(ssrc + j);
        for (u32 q = 1; q < nq; q++) {
          uint4 iN = *(const uint4*)(ssrc + j + 4);   // prefetch next quad's indices
          uint2 v0 = *(const uint2*)(xq + ((size_t)iA.x << 5) + (cl << 1));
          uint2 v1 = *(const uint2*)(xq + ((size_t)iA.y << 5) + (cl << 1));
          uint2 v2 = *(const uint2*)(xq + ((size_t)iA.z << 5) + (cl << 1));
          uint2 v3 = *(const uint2*)(xq + ((size_t)iA.w << 5) + (cl << 1));
          DECV(v0, A0, A1, A2, A3) DECV(v1, A0, A1, A2, A3)
          DECV(v2, A0, A1, A2, A3) DECV(v3, A0, A1, A2, A3)
          iA = iN; j += 4;
        }
        {
          uint2 v0 = *(const uint2*)(xq + ((size_t)iA.x << 5) + (cl << 1));
          uint2 v1 = *(const uint2*)(xq + ((size_t)iA.y << 5) + (cl << 1));
          uint2 v2 = *(const uint2*)(xq + ((size_t)iA.z << 5) + (cl << 1));
          uint2 v3 = *(const uint2*)(xq + ((size_t)iA.w << 5) + (cl << 1));
          DECV(v0, A0, A1, A2, A3) DECV(v1, A0, A1, A2, A3)
          DECV(v2, A0, A1, A2, A3) DECV(v3, A0, A1, A2, A3)
          j += 4;
        }
      }
      for (; j < s1; j++) {
        int e = ssrc[j];
        uint2 v = *(const uint2*)(xq + ((size_t)e << 5) + (cl << 1));
        DECV(v, A0, A1, A2, A3)
      }
    }
    float inv = 1.0f / (float)(deg ? deg : 1u);
    u32 o0 = __builtin_bit_cast(u32, __builtin_amdgcn_cvt_pkrtz(A0.x * inv, A0.y * inv));
    u32 o1 = __builtin_bit_cast(u32, __builtin_amdgcn_cvt_pkrtz(A1.x * inv, A1.y * inv));
    u32 o2 = __builtin_bit_cast(u32, __builtin_amdgcn_cvt_pkrtz(A2.x * inv, A2.y * inv));
    u32 o3 = __builtin_bit_cast(u32, __builtin_amdgcn_cvt_pkrtz(A3.x * inv, A3.y * inv));
    *(uint4*)&mlds[ln][cl * 8] = uint4{o0, o1, o2, o3};   // 16 lanes cover 128 f16 feats
  }
  __syncthreads();

  // ---- phase 2: 2 strips x 2 col-halves; wave = (strip, half); f16 MFMA ----
  int la = lane & 15, lb = lane >> 4;
  int strip = wv & 1, ch = wv >> 1;
  int rbase = nbase + strip * 16;
  half8 a[8];
  const u16* ab = xh + ((size_t)(rbase + la) << 7) + lb * 8;
#pragma unroll
  for (int kb = 0; kb < 4; kb++) a[kb] = *(const half8*)(ab + kb * 32);
#pragma unroll
  for (int kb = 0; kb < 4; kb++)
    a[4 + kb] = *(const half8*)(&mlds[strip * 16 + la][kb * 32 + lb * 8]);

#pragma unroll
  for (int c = 0; c < 4; c++) {
    int ct = ch * 4 + c;
    f32x4 acc = { 0.f, 0.f, 0.f, 0.f };
    const u16* bbase = wh + ((size_t)(ct * 16 + la) << 8) + lb * 8;
#pragma unroll
    for (int kb = 0; kb < 8; kb++) {
      half8 b = *(const half8*)(bbase + kb * 32);
      acc = __builtin_amdgcn_mfma_f32_16x16x32_f16(a[kb], b, acc, 0, 0, 0);
    }
    float bc = bias[ct * 16 + la];
#pragma unroll
    for (int jj = 0; jj < 4; jj++) {
      int rr = rbase + lb * 4 + jj;
      if (rr < N) out[((size_t)rr << 7) + ct * 16 + la] = acc[jj] + bc;
    }
  }
}

extern "C" void kernel_launch(void* const* d_in, const int* in_sizes, int n_in,
                              void* d_out, int out_size, void* d_ws, size_t ws_size,
                              hipStream_t stream) {
  const float* x    = (const float*)d_in[0];
  const int*   ei   = (const int*)d_in[1];
  const float* W    = (const float*)d_in[2];
  const float* bias = (const float*)d_in[3];
  const int N = in_sizes[0] / 128;
  const int E = in_sizes[1] / 2;
  const int nbkt = (N + 255) >> 8;           // 256-node buckets
  const int* src = ei;
  const int* dst = ei + E;
  float* out = (float*)d_out;

  // transient CSR-build scratch in d_out (dead before fuse_k writes out):
  u32* packed   = (u32*)d_out;               // E
  u32* bktTotal = packed + E;                // nbkt
  u32* start    = bktTotal + nbkt;           // nbkt+1
  u32* cursor   = start + nbkt + 1;          // nbkt

  char* ws = (char*)d_ws;
  u32* offsets = (u32*)ws;                   // N+1
  size_t off = ((size_t)(N + 1) * 4 + 255) & ~(size_t)255;
  int* ssrc = (int*)(ws + off);              // E
  off += (size_t)E * 4;
  off = (off + 255) & ~(size_t)255;
  u16* xh = (u16*)(ws + off);                // N*128 f16 (GEMM A-half)
  off += (size_t)N * 128 * 2;
  off = (off + 255) & ~(size_t)255;
  u32* xq = (u32*)(ws + off);                // N*32 u32 (fp8 gather table)
  off += (size_t)N * 128;
  off = (off + 255) & ~(size_t)255;
  u16* wh = (u16*)(ws + off);                // 128*256 f16
  off += (size_t)128 * 256 * 2;
  off = (off + 255) & ~(size_t)255;
  u8* nodeperm = (u8*)(ws + off);            // nbkt*256 bytes

  const int nbx = (N * 32 + 255) / 256;
  const int nba = (E + 8191) / 8192;
  hipMemsetAsync(bktTotal, 0, (size_t)nbkt * 4, stream);
  pre_k<<<nba + nbx + 32, 256, 0, stream>>>(x, xh, xq, W, wh, dst, E, bktTotal, N, nbkt, nba, nbx);
  bscan_k<<<1, 512, 0, stream>>>(bktTotal, nbkt, E, N, start, cursor, offsets);
  part_k<<<nba, 256, 0, stream>>>(src, dst, E, cursor, packed, nbkt);
  bucket_k<<<nbkt, 256, 0, stream>>>(packed, start, N, offsets, ssrc, nodeperm);
  fuse_k<<<(N + 31) / 32, 256, 0, stream>>>(ssrc, offsets, xq, xh, wh, bias, nodeperm, out, N);
}